// Round 6
// baseline (115.300 us; speedup 1.0000x reference)
//
#include <hip/hip_runtime.h>
#include <hip/hip_bf16.h>

// CriticHead fused, round 6: occupancy probe — 8 tasks/block, 512 blocks.
//
// Math (verified R1 fp32 absmax 0; R2-R5 bf16 absmax 1.5 < 2.0):
//   feat[t] = [outer3(res,fr,estep)(150) | backbone(768)]  (W1 row order)
//   y2 = relu(feat @ W1 + b1);  y41 = y2*mean(enode);  y42 = y2*(sum ccl)(sum cnd)
//   heads -> y = (1-p)*(-100) + p*(y61+y62), p = sig(me*d3+b3)*sig(sc*d5+b5)
//
// R2-R5 (105.9-113.3) are insensitive to W1-path structure. Untested axis:
// parallelism. R6: grid 512 blocks (2/CU, 4 waves/SIMD) with 8 tasks/block so
// co-resident blocks overlap each other's serial phases (HBM stage / barrier /
// MFMA / heads). B per (chunk,quad,ncol), A values, MFMA order, head math all
// bitwise-identical to R5 -> absmax stays 1.5. A-rows 8..15 of each MFMA read
// uninitialized LDS; their D rows are unused (row-independent dot products).

typedef __bf16  bf16x8 __attribute__((ext_vector_type(8)));
typedef float   f32x4  __attribute__((ext_vector_type(4)));
typedef unsigned int uintx4 __attribute__((ext_vector_type(4)));
typedef unsigned short ushort4e __attribute__((ext_vector_type(4)));

#define FAILC -100.0f
#define ASTRIDE 936         // LDS feat row stride in bf16 (16B-aligned rows)

static __device__ __forceinline__ unsigned short f2bf(float f) {
    unsigned u = __builtin_bit_cast(unsigned, f);
    u = (u + 0x7FFFu + ((u >> 16) & 1u)) >> 16;   // RNE
    return (unsigned short)u;
}

__global__ __launch_bounds__(512) void critic_fused(
    const float* __restrict__ bb,     // [T,768]
    const float* __restrict__ res,    // [T,5]
    const float* __restrict__ fr,     // [T,5]
    const float* __restrict__ estep,  // [T,6]
    const float* __restrict__ enode,  // [T,64]
    const float* __restrict__ ccl,    // [T,4]
    const float* __restrict__ cnd,    // [T,32]
    const float* __restrict__ W1,     // [918,128]
    const float* __restrict__ b1,     // [128]
    const float* __restrict__ W3, const float* __restrict__ b3,
    const float* __restrict__ W4, const float* __restrict__ b4,
    const float* __restrict__ W5, const float* __restrict__ b5,
    const float* __restrict__ W6, const float* __restrict__ b6,
    float* __restrict__ out)          // [T]
{
    // 16 rows allocated so MFMA A-reads for rows 8..15 stay inside our LDS
    // block (they produce unused D rows). Only rows 0..7 are initialized.
    __shared__ unsigned short a_lds[16 * ASTRIDE];  // bf16 feat, K-permuted
    __shared__ float s_y2[16][132];                 // relu(fc1) fp32

    const int t = threadIdx.x;
    const int task0 = blockIdx.x * 8;               // 8 tasks per block

    const int lane = t & 63;
    const int wave = t >> 6;
    const int mrow = lane & 15;
    const int quad = lane >> 4;
    const int ncol = wave * 16 + mrow;

    // ---- issue ALL global reads up front (overlap HBM round trips) ----
    const float4* bbp = (const float4*)(bb + (size_t)task0 * 768);
    float4 bbv[3];                                  // 8*192 = 1536 float4s
#pragma unroll
    for (int it = 0; it < 3; ++it) bbv[it] = bbp[t + it * 512];

    // outer-product factors: 8 tasks x 150 slots = 1200 (+80 pad) over 3 passes
    float ov0[3], ov1[3], ov2[3];
#pragma unroll
    for (int it = 0; it < 3; ++it) {
        int w = t + it * 512;                       // 0..1535
        if (w < 1200) {
            int r = w / 150;
            int idx = w - r * 150;
            int n = idx / 30;
            int rem = idx - n * 30;
            int m = rem / 6;
            int o = rem - m * 6;
            int tg = task0 + r;
            ov0[it] = res[tg * 5 + n];
            ov1[it] = fr[tg * 5 + m];
            ov2[it] = estep[tg * 6 + o];
        }
    }

    // ---- write backbone -> bf16 LDS cols [0,768), rows 0..7 ----
#pragma unroll
    for (int it = 0; it < 3; ++it) {
        int i = t + it * 512;          // 0..1535
        int m = i / 192;               // task row 0..7
        int off = (i - m * 192) * 4;   // col in [0,768)
        float4 v = bbv[it];
        ushort4e pk = { f2bf(v.x), f2bf(v.y), f2bf(v.z), f2bf(v.w) };
        *(ushort4e*)&a_lds[m * ASTRIDE + off] = pk;
    }

    // outer products -> cols [768,918); zero pad cols [918,928), rows 0..7
#pragma unroll
    for (int it = 0; it < 3; ++it) {
        int w = t + it * 512;
        if (w < 1200) {
            int r = w / 150;
            int idx = w - r * 150;
            float v = ov0[it] * ov1[it] * ov2[it];
            a_lds[r * ASTRIDE + 768 + idx] = f2bf(v);
        } else if (w < 1280) {
            int z = w - 1200;              // 0..79
            int r = z / 10;
            a_lds[r * ASTRIDE + 918 + (z - r * 10)] = 0;
        }
    }
    __syncthreads();   // single pre-MFMA barrier

    // ---- MFMA loop: A from LDS, B gathered from W1 with rolling prefetch.
    // frag j of chunk c: B[k=32c+quad*8+j][ncol]; permuted K: k<768 -> row
    // 150+k, 768<=k<918 -> row k-768, else 0.
    const unsigned short* aptr = a_lds + mrow * ASTRIDE + quad * 8;

    float bw[4][8];    // 4-slot window, prefetch depth 3
#pragma unroll
    for (int c = 0; c < 3; ++c) {
        const int kq0 = c * 32 + quad * 8;
#pragma unroll
        for (int j = 0; j < 8; ++j) {
            int k = kq0 + j;
            int row = (k < 768) ? (150 + k) : (k - 768);
            bw[c][j] = (k < 918) ? W1[(size_t)row * 128 + ncol] : 0.0f;
        }
    }

    f32x4 acc = {0.f, 0.f, 0.f, 0.f};
#pragma unroll
    for (int c = 0; c < 29; ++c) {
        const int slot = c & 3;
        uintx4 bp;
        bp.x = (unsigned)f2bf(bw[slot][0]) | ((unsigned)f2bf(bw[slot][1]) << 16);
        bp.y = (unsigned)f2bf(bw[slot][2]) | ((unsigned)f2bf(bw[slot][3]) << 16);
        bp.z = (unsigned)f2bf(bw[slot][4]) | ((unsigned)f2bf(bw[slot][5]) << 16);
        bp.w = (unsigned)f2bf(bw[slot][6]) | ((unsigned)f2bf(bw[slot][7]) << 16);
        if (c + 3 < 29) {
            const int cn = c + 3;
            const int sn = cn & 3;
            const int kq0 = cn * 32 + quad * 8;
#pragma unroll
            for (int j = 0; j < 8; ++j) {
                int k = kq0 + j;
                int row = (k < 768) ? (150 + k) : (k - 768);
                bw[sn][j] = (k < 918) ? W1[(size_t)row * 128 + ncol] : 0.0f;
            }
        }
        uintx4 au = *(const uintx4*)(aptr + c * 32);
        acc = __builtin_amdgcn_mfma_f32_16x16x32_bf16(
            __builtin_bit_cast(bf16x8, au), __builtin_bit_cast(bf16x8, bp),
            acc, 0, 0, 0);
    }

    // epilogue: bias + relu -> s_y2.  D layout: col=lane&15, row=quad*4+reg.
    // Rows 8..15 hold garbage (unused).
    {
        float bias = b1[ncol];
#pragma unroll
        for (int r = 0; r < 4; ++r) {
            int m = quad * 4 + r;
            s_y2[m][ncol] = fmaxf(acc[r] + bias, 0.f);
        }
    }
    __syncthreads();

    // ---- heads (identical math to R1-R5); 8 tasks -> threads 0..255 ----
    if (t < 256) {
        const int kq = t & 31;
        const int rsub = t >> 5;          // 0..7
        const int tg = task0 + rsub;
        const int k4 = kq * 4;

        float4 yv = *(const float4*)&s_y2[rsub][k4];
        float y0 = yv.x, y1 = yv.y, y2v = yv.z, y3 = yv.w;

        float4 w3v = *(const float4*)(W3 + k4);
        float4 w4v = *(const float4*)(W4 + k4);
        float4 w5v = *(const float4*)(W5 + k4);
        float4 w6v = *(const float4*)(W6 + k4);
        float pd3 = y0 * w3v.x + y1 * w3v.y + y2v * w3v.z + y3 * w3v.w;
        float pd4 = y0 * w4v.x + y1 * w4v.y + y2v * w4v.z + y3 * w4v.w;
        float pd5 = y0 * w5v.x + y1 * w5v.y + y2v * w5v.z + y3 * w5v.w;
        float pd6 = y0 * w6v.x + y1 * w6v.y + y2v * w6v.z + y3 * w6v.w;

        const float* en = enode + (size_t)tg * 64 + kq * 2;
        float pe = en[0] + en[1];
        float pc = (kq < 4) ? ccl[tg * 4 + kq] : 0.f;
        float pn = cnd[tg * 32 + kq];

#pragma unroll
        for (int m = 1; m < 32; m <<= 1) {
            pd3 += __shfl_xor(pd3, m);
            pd4 += __shfl_xor(pd4, m);
            pd5 += __shfl_xor(pd5, m);
            pd6 += __shfl_xor(pd6, m);
            pe  += __shfl_xor(pe, m);
            pc  += __shfl_xor(pc, m);
            pn  += __shfl_xor(pn, m);
        }

        if (kq == 0) {
            float me = pe * (1.0f / 64.0f);
            float sc = pc * pn;
            float a3 = me * pd3 + b3[0];
            float a5 = sc * pd5 + b5[0];
            float y51 = 1.0f / (1.0f + __expf(-a3));
            float y52 = 1.0f / (1.0f + __expf(-a5));
            float y61 = me * pd4 + b4[0];
            float y62 = sc * pd6 + b6[0];
            float p = y51 * y52;
            out[tg] = (1.0f - p) * FAILC + p * (y61 + y62);
        }
    }
}

extern "C" void kernel_launch(void* const* d_in, const int* in_sizes, int n_in,
                              void* d_out, int out_size, void* d_ws, size_t ws_size,
                              hipStream_t stream) {
    const float* bb    = (const float*)d_in[2];
    const float* res   = (const float*)d_in[3];
    const float* fr    = (const float*)d_in[4];
    const float* estep = (const float*)d_in[5];
    const float* enode = (const float*)d_in[6];
    const float* ccl   = (const float*)d_in[7];
    const float* cnd   = (const float*)d_in[8];
    const float* W1    = (const float*)d_in[9];
    const float* b1    = (const float*)d_in[10];
    const float* W3    = (const float*)d_in[11];
    const float* b3    = (const float*)d_in[12];
    const float* W4    = (const float*)d_in[13];
    const float* b4    = (const float*)d_in[14];
    const float* W5    = (const float*)d_in[15];
    const float* b5    = (const float*)d_in[16];
    const float* W6    = (const float*)d_in[17];
    const float* b6    = (const float*)d_in[18];
    float* out = (float*)d_out;

    int T = in_sizes[3] / 5;      // y_res is [T,5]
    int blocks = T / 8;           // 8 tasks per block -> 512 blocks (2/CU)

    hipLaunchKernelGGL(critic_fused, dim3(blocks), dim3(512), 0, stream,
                       bb, res, fr, estep, enode, ccl, cnd,
                       W1, b1, W3, b3, W4, b4, W5, b5, W6, b6, out);
}

// Round 7
// 105.587 us; speedup vs baseline: 1.0920x; 1.0920x over previous
//
#include <hip/hip_runtime.h>
#include <hip/hip_bf16.h>

// CriticHead fused, round 7: resubmit of R2 (measured best, 105.9 us).
//
// Math (verified R1 fp32 absmax 0; R2-R6 bf16 absmax 1.5 < 2.0):
//   feat[t] = [outer3(res,fr,estep)(150) | backbone(768)]  (W1 row order)
//   y2 = relu(feat @ W1 + b1);  y41 = y2*mean(enode);  y42 = y2*(sum ccl)(sum cnd)
//   heads -> y = (1-p)*(-100) + p*(y61+y62), p = sig(me*d3+b3)*sig(sc*d5+b5)
//
// Session conclusion: dur_us is dominated by harness-fixed graph nodes
// (268 MB ws poison-fill at 83% HBM peak = ~41 us, ~19 restore nodes, memsets
// ~= 100 us total); the kernel itself is ~6 us ~= its cold-memory floor
// (13.3 MB @ 6.3 TB/s + 0.4 us MFMA + launch). Six structurally independent
// kernel variants (R1-R6) land 105.9-115.3; everything since R2 is noise.
// This file is the measured-best variant (R2), resubmitted to pin the best
// configuration: prep kernel swizzles W1 -> bf16 B-fragments in d_ws, main
// kernel is LDS-A + coalesced-B mfma_f32_16x16x32_bf16 with fused epilogue.

typedef __bf16  bf16x8 __attribute__((ext_vector_type(8)));
typedef float   f32x4  __attribute__((ext_vector_type(4)));
typedef unsigned int uintx4 __attribute__((ext_vector_type(4)));
typedef unsigned short ushort4e __attribute__((ext_vector_type(4)));

#define FAILC -100.0f
#define ASTRIDE 936         // LDS feat row stride in bf16 (16B-aligned rows)

static __device__ __forceinline__ unsigned short f2bf(float f) {
    unsigned u = __builtin_bit_cast(unsigned, f);
    u = (u + 0x7FFFu + ((u >> 16) & 1u)) >> 16;   // RNE
    return (unsigned short)u;
}

// ---- kernel 1: W1 fp32 -> bf16, permuted K, B-fragment-swizzled into ws ----
// frag element j of (c,h,lane): B[k=32c+(lane>>4)*8+j][n=16h+(lane&15)]
// with k in permuted order: k<768 -> W1 row 150+k; 768<=k<918 -> row k-768; else 0.
__global__ __launch_bounds__(256) void critic_prep(
    const float* __restrict__ W1, unsigned short* __restrict__ wsB)
{
    int tid = blockIdx.x * 256 + threadIdx.x;   // 29*8*64 = 14848 total
    int l = tid & 63;
    int h = (tid >> 6) & 7;
    int c = tid >> 9;
    int n = h * 16 + (l & 15);
    int kbase = c * 32 + (l >> 4) * 8;
    unsigned short v[8];
#pragma unroll
    for (int j = 0; j < 8; ++j) {
        int p = kbase + j;
        float f;
        if (p < 768)      f = W1[(size_t)(150 + p) * 128 + n];
        else if (p < 918) f = W1[(size_t)(p - 768) * 128 + n];
        else              f = 0.0f;
        v[j] = f2bf(f);
    }
    uintx4 pk;
    pk.x = (unsigned)v[0] | ((unsigned)v[1] << 16);
    pk.y = (unsigned)v[2] | ((unsigned)v[3] << 16);
    pk.z = (unsigned)v[4] | ((unsigned)v[5] << 16);
    pk.w = (unsigned)v[6] | ((unsigned)v[7] << 16);
    *(uintx4*)(wsB + (size_t)tid * 8) = pk;
}

// ---- kernel 2: fused main ----
__global__ __launch_bounds__(512) void critic_main(
    const float* __restrict__ bb,     // [T,768]
    const float* __restrict__ res,    // [T,5]
    const float* __restrict__ fr,     // [T,5]
    const float* __restrict__ estep,  // [T,6]
    const float* __restrict__ enode,  // [T,64]
    const float* __restrict__ ccl,    // [T,4]
    const float* __restrict__ cnd,    // [T,32]
    const unsigned short* __restrict__ wsB,  // swizzled bf16 W1
    const float* __restrict__ b1,     // [128]
    const float* __restrict__ W3, const float* __restrict__ b3,
    const float* __restrict__ W4, const float* __restrict__ b4,
    const float* __restrict__ W5, const float* __restrict__ b5,
    const float* __restrict__ W6, const float* __restrict__ b6,
    float* __restrict__ out)          // [T]
{
    __shared__ unsigned short a_lds[16 * ASTRIDE];  // bf16 feat, K-permuted
    __shared__ float s_y2[16][132];                 // relu(fc1) fp32
    __shared__ float s_small[16][16];               // res(5) fr(5) estep(6)

    const int t = threadIdx.x;
    const int task0 = blockIdx.x * 16;

    // stage small vectors
    if (t < 256) {
        int r = t >> 4, q = t & 15;
        int tg = task0 + r;
        float v;
        if (q < 5)       v = res[tg * 5 + q];
        else if (q < 10) v = fr[tg * 5 + (q - 5)];
        else             v = estep[tg * 6 + (q - 10)];
        s_small[r][q] = v;
    }

    // stage backbone -> bf16 LDS cols [0,768). 3072 float4s, 6 per thread.
    {
        const float4* bbp = (const float4*)(bb + (size_t)task0 * 768);
#pragma unroll
        for (int it = 0; it < 6; ++it) {
            int i = t + it * 512;          // 0..3071
            int m = i / 192;               // task row
            int off = (i - m * 192) * 4;   // col in [0,768)
            float4 v = bbp[i];
            ushort4e pk = { f2bf(v.x), f2bf(v.y), f2bf(v.z), f2bf(v.w) };
            *(ushort4e*)&a_lds[m * ASTRIDE + off] = pk;
        }
    }
    __syncthreads();

    // outer products -> cols [768,918); zero pad cols [918,928)
    for (int w = t; w < 2560; w += 512) {
        if (w < 2400) {
            int r = w / 150;
            int idx = w - r * 150;
            int n = idx / 30;
            int rem = idx - n * 30;
            int m = rem / 6;
            int o = rem - m * 6;
            float v = s_small[r][n] * s_small[r][5 + m] * s_small[r][10 + o];
            a_lds[r * ASTRIDE + 768 + idx] = f2bf(v);
        } else {
            int z = w - 2400;              // 0..159
            int r = z / 10;
            a_lds[r * ASTRIDE + 918 + (z - r * 10)] = 0;
        }
    }
    __syncthreads();

    // ---- MFMA main loop: wave w computes D[16 tasks][16 cols], n0 = 16w ----
    const int lane = t & 63;
    const int wave = t >> 6;
    const int mrow = lane & 15;
    const int quad = lane >> 4;

    const unsigned short* aptr = a_lds + mrow * ASTRIDE + quad * 8;
    const unsigned short* bptr = wsB + (size_t)(wave * 64 + lane) * 8;

    f32x4 acc = {0.f, 0.f, 0.f, 0.f};
    uintx4 bnext = *(const uintx4*)bptr;
#pragma unroll
    for (int c = 0; c < 29; ++c) {
        uintx4 bcur = bnext;
        if (c < 28) bnext = *(const uintx4*)(bptr + (size_t)(c + 1) * 4096);
        uintx4 au = *(const uintx4*)(aptr + c * 32);
        acc = __builtin_amdgcn_mfma_f32_16x16x32_bf16(
            __builtin_bit_cast(bf16x8, au), __builtin_bit_cast(bf16x8, bcur),
            acc, 0, 0, 0);
    }

    // epilogue: bias + relu -> s_y2.  D layout: col=lane&15, row=quad*4+reg.
    {
        int n = wave * 16 + mrow;
        float bias = b1[n];
#pragma unroll
        for (int r = 0; r < 4; ++r) {
            int m = quad * 4 + r;
            s_y2[m][n] = fmaxf(acc[r] + bias, 0.f);
        }
    }
    __syncthreads();

    // ---- heads (identical math to R1, which validated absmax 0) ----
    const int kq = t & 31;
    const int rsub = t >> 5;
    const int tg = task0 + rsub;
    const int k4 = kq * 4;

    float4 yv = *(const float4*)&s_y2[rsub][k4];
    float y0 = yv.x, y1 = yv.y, y2v = yv.z, y3 = yv.w;

    float4 w3v = *(const float4*)(W3 + k4);
    float4 w4v = *(const float4*)(W4 + k4);
    float4 w5v = *(const float4*)(W5 + k4);
    float4 w6v = *(const float4*)(W6 + k4);
    float pd3 = y0 * w3v.x + y1 * w3v.y + y2v * w3v.z + y3 * w3v.w;
    float pd4 = y0 * w4v.x + y1 * w4v.y + y2v * w4v.z + y3 * w4v.w;
    float pd5 = y0 * w5v.x + y1 * w5v.y + y2v * w5v.z + y3 * w5v.w;
    float pd6 = y0 * w6v.x + y1 * w6v.y + y2v * w6v.z + y3 * w6v.w;

    const float* en = enode + (size_t)tg * 64 + kq * 2;
    float pe = en[0] + en[1];
    float pc = (kq < 4) ? ccl[tg * 4 + kq] : 0.f;
    float pn = cnd[tg * 32 + kq];

#pragma unroll
    for (int m = 1; m < 32; m <<= 1) {
        pd3 += __shfl_xor(pd3, m);
        pd4 += __shfl_xor(pd4, m);
        pd5 += __shfl_xor(pd5, m);
        pd6 += __shfl_xor(pd6, m);
        pe  += __shfl_xor(pe, m);
        pc  += __shfl_xor(pc, m);
        pn  += __shfl_xor(pn, m);
    }

    if (kq == 0) {
        float me = pe * (1.0f / 64.0f);
        float sc = pc * pn;
        float a3 = me * pd3 + b3[0];
        float a5 = sc * pd5 + b5[0];
        float y51 = 1.0f / (1.0f + __expf(-a3));
        float y52 = 1.0f / (1.0f + __expf(-a5));
        float y61 = me * pd4 + b4[0];
        float y62 = sc * pd6 + b6[0];
        float p = y51 * y52;
        out[tg] = (1.0f - p) * FAILC + p * (y61 + y62);
    }
}

extern "C" void kernel_launch(void* const* d_in, const int* in_sizes, int n_in,
                              void* d_out, int out_size, void* d_ws, size_t ws_size,
                              hipStream_t stream) {
    const float* bb    = (const float*)d_in[2];
    const float* res   = (const float*)d_in[3];
    const float* fr    = (const float*)d_in[4];
    const float* estep = (const float*)d_in[5];
    const float* enode = (const float*)d_in[6];
    const float* ccl   = (const float*)d_in[7];
    const float* cnd   = (const float*)d_in[8];
    const float* W1    = (const float*)d_in[9];
    const float* b1    = (const float*)d_in[10];
    const float* W3    = (const float*)d_in[11];
    const float* b3    = (const float*)d_in[12];
    const float* W4    = (const float*)d_in[13];
    const float* b4    = (const float*)d_in[14];
    const float* W5    = (const float*)d_in[15];
    const float* b5    = (const float*)d_in[16];
    const float* W6    = (const float*)d_in[17];
    const float* b6    = (const float*)d_in[18];
    float* out = (float*)d_out;
    unsigned short* wsB = (unsigned short*)d_ws;   // 237,568 B used

    int T = in_sizes[3] / 5;      // y_res is [T,5]
    int blocks = T / 16;          // 16 tasks per block

    hipLaunchKernelGGL(critic_prep, dim3(58), dim3(256), 0, stream, W1, wsB);
    hipLaunchKernelGGL(critic_main, dim3(blocks), dim3(512), 0, stream,
                       bb, res, fr, estep, enode, ccl, cnd,
                       wsB, b1, W3, b3, W4, b4, W5, b5, W6, b6, out);
}